// Round 8
// baseline (915.761 us; speedup 1.0000x reference)
//
#include <hip/hip_runtime.h>
#include <hip/hip_bf16.h>
#include <hip/hip_cooperative_groups.h>
#include <stdint.h>

namespace cg = cooperative_groups;

typedef __attribute__((ext_vector_type(8))) short short8;
typedef __attribute__((ext_vector_type(4))) float f32x4;

#define D 256
#define NTY 4  // y-tiles (128 cols) per block in k_gemm

static __device__ __forceinline__ float b2f(unsigned short u) {
  union { unsigned u; float f; } c; c.u = ((unsigned)u) << 16; return c.f;
}
static __device__ __forceinline__ unsigned f2b(float f) {
  union { float f; unsigned u; } c; c.f = f;
  return (c.u + 0x7FFFu + ((c.u >> 16) & 1u)) >> 16;
}

// async global->LDS, 16B per lane, wave-uniform LDS base + lane*16
static __device__ __forceinline__ void gload16(const void* g, void* l) {
  __builtin_amdgcn_global_load_lds(
      (const __attribute__((address_space(1))) unsigned int*)g,
      (__attribute__((address_space(3))) unsigned int*)l, 16, 0, 0);
}

// ---------------- cooperative prep: cvt + CSR build in ONE dispatch --------
// Phases separated by grid.sync():
//  0: cvt x (fp32->bf16, pad) | cvt W -> Wt[(r*256+o)][i] | zero deg
//  1: deg atomics
//  2: per-block reduce of deg chunks -> bsum
//  3: block 0 scans bsum -> boff (+ total -> rowptr[Nn])
//  4: per-block exclusive scan -> rowptr, cursor
//  5: scatter-bin -> ect (col | type<<20)
__global__ __launch_bounds__(256) void k_prep(
    const float* __restrict__ x, unsigned short* __restrict__ xb,
    long n_elems, long pad_elems,
    const float* __restrict__ w, unsigned short* __restrict__ wt, int wtot,
    const int* __restrict__ ei, const int* __restrict__ et, int E,
    int* deg, int* bsum, int* boff, int* rowptr, int* cursor,
    unsigned* ect, int Nn, int nsc) {
  cg::grid_group grid = cg::this_grid();
  __shared__ int sm[256];
  const int t = threadIdx.x;
  const int gtid = blockIdx.x * 256 + t;
  const int gsz = gridDim.x * 256;

  // phase 0: converts + zero
  for (int i = gtid; i < Nn; i += gsz) deg[i] = 0;
  for (long i4 = gtid; i4 * 4 < pad_elems; i4 += gsz) {
    ushort4 o;
    if (i4 * 4 < n_elems) {
      float4 v = ((const float4*)x)[i4];
      o.x = f2b(v.x); o.y = f2b(v.y); o.z = f2b(v.z); o.w = f2b(v.w);
    } else {
      o.x = 0; o.y = 0; o.z = 0; o.w = 0;
    }
    ((ushort4*)xb)[i4] = o;
  }
  for (int q = gtid; q < wtot; q += gsz) {
    int i = q & 255;          // k index
    int orow = q >> 8;        // r*256 + o
    int r = orow >> 8, o = orow & 255;
    wt[q] = (unsigned short)f2b(w[((size_t)(r * 256 + i)) * 256 + o]);
  }
  grid.sync();

  // phase 1: degree count
  for (int e = gtid; e < E; e += gsz) atomicAdd(&deg[ei[e]], 1);
  grid.sync();

  // phase 2: block-chunk reduce (blocks 0..nsc-1, 256 deg each)
  if (blockIdx.x < (unsigned)nsc) {
    int idx = blockIdx.x * 256 + t;
    sm[t] = idx < Nn ? deg[idx] : 0;
    __syncthreads();
    for (int off = 128; off; off >>= 1) {
      if (t < off) sm[t] += sm[t + off];
      __syncthreads();
    }
    if (t == 0) bsum[blockIdx.x] = sm[0];
  }
  grid.sync();

  // phase 3: block 0 scans bsum (nsc <= 256)
  if (blockIdx.x == 0) {
    int v = t < nsc ? bsum[t] : 0;
    sm[t] = v;
    __syncthreads();
    for (int off = 1; off < 256; off <<= 1) {
      int xv = t >= off ? sm[t - off] : 0;
      __syncthreads();
      sm[t] += xv;
      __syncthreads();
    }
    if (t < nsc) boff[t] = sm[t] - v;
    if (t == nsc - 1) rowptr[Nn] = sm[t];
  }
  grid.sync();

  // phase 4: per-block exclusive scan -> rowptr/cursor
  if (blockIdx.x < (unsigned)nsc) {
    int idx = blockIdx.x * 256 + t;
    int v = idx < Nn ? deg[idx] : 0;
    sm[t] = v;
    __syncthreads();
    for (int off = 1; off < 256; off <<= 1) {
      int xv = t >= off ? sm[t - off] : 0;
      __syncthreads();
      sm[t] += xv;
      __syncthreads();
    }
    if (idx < Nn) {
      int e0 = boff[blockIdx.x] + sm[t] - v;
      rowptr[idx] = e0;
      cursor[idx] = e0;
    }
  }
  grid.sync();

  // phase 5: scatter-bin
  for (int e = gtid; e < E; e += gsz) {
    int r = ei[e], c = ei[E + e], ty = et[e];
    int pos = atomicAdd(&cursor[r], 1);
    ect[pos] = (unsigned)c | ((unsigned)ty << 20);
  }
}

// ---------------- GEMM: xt = xb @ Wt^T, A-resident, N-loop inside block ----
// PROVEN round-5/6 kernel (91 µs, VGPR=80, no spill) — unchanged.
__global__ __launch_bounds__(256) void k_gemm(const unsigned short* __restrict__ A,
                                              const unsigned short* __restrict__ B,
                                              unsigned short* __restrict__ C,
                                              int ldc) {
  __shared__ __align__(16) char lA[64 * 512];    // [64 rows][32 chunks of 16B]
  __shared__ __align__(16) char lB[128 * 128];   // [128 rows][8 chunks of 16B]
  const int t = threadIdx.x;
  const int lane = t & 63;
  const int wave = t >> 6;
  const int l15 = lane & 15, lhi = lane >> 4;
  const size_t tm = (size_t)blockIdx.x * 64;
  const int y0 = blockIdx.y * NTY;

#pragma unroll
  for (int it = 0; it < 8; ++it) {
    int s = it * 256 + t;
    int row = s >> 5, c = s & 31;
    gload16(A + (tm + row) * 256 + ((c ^ (row & 7)) * 8),
            lA + (it * 256 + wave * 64) * 16);
  }

  for (int y = y0; y < y0 + NTY; ++y) {
    const int tn = y * 128;
    f32x4 acc[4][2];
#pragma unroll
    for (int a = 0; a < 4; ++a)
#pragma unroll
      for (int b = 0; b < 2; ++b)
#pragma unroll
        for (int e = 0; e < 4; ++e) acc[a][b][e] = 0.f;

    for (int kt = 0; kt < 256; kt += 64) {
      __syncthreads();
#pragma unroll
      for (int it = 0; it < 4; ++it) {
        int s = it * 256 + t;
        int row = s >> 3, c = s & 7;
        gload16(B + (tn + row) * 256 + kt + ((c ^ (row & 7)) * 8),
                lB + (it * 256 + wave * 64) * 16);
      }
      __syncthreads();

      short8 af[4][2], bfv[2][2];
      const int ktc = kt >> 3;
#pragma unroll
      for (int mi = 0; mi < 4; ++mi) {
#pragma unroll
        for (int kk = 0; kk < 2; ++kk) {
          int R = mi * 16 + l15;
          int c = ktc + kk * 4 + lhi;
          af[mi][kk] = *(const short8*)(lA + R * 512 + ((c ^ (R & 7)) * 16));
        }
      }
#pragma unroll
      for (int ni = 0; ni < 2; ++ni) {
#pragma unroll
        for (int kk = 0; kk < 2; ++kk) {
          int R2 = wave * 32 + ni * 16 + l15;
          int c2 = kk * 4 + lhi;
          bfv[ni][kk] = *(const short8*)(lB + R2 * 128 + ((c2 ^ (R2 & 7)) * 16));
        }
      }
#pragma unroll
      for (int mi = 0; mi < 4; ++mi) {
#pragma unroll
        for (int ni = 0; ni < 2; ++ni) {
          acc[mi][ni] = __builtin_amdgcn_mfma_f32_16x16x32_bf16(af[mi][0], bfv[ni][0], acc[mi][ni], 0, 0, 0);
          acc[mi][ni] = __builtin_amdgcn_mfma_f32_16x16x32_bf16(af[mi][1], bfv[ni][1], acc[mi][ni], 0, 0, 0);
        }
      }
    }
#pragma unroll
    for (int mi = 0; mi < 4; ++mi) {
#pragma unroll
      for (int j = 0; j < 4; ++j) {
        size_t row = tm + mi * 16 + lhi * 4 + j;
        unsigned pk = f2b(acc[mi][0][j]) | (f2b(acc[mi][1][j]) << 16);
        *(unsigned*)(C + row * (size_t)ldc + tn + wave * 32 + l15 * 2) = pk;
      }
    }
  }
}

// ---------------- gather v2 (round-6 proven, unchanged) --------------------
__global__ __launch_bounds__(256) void k_gather(const unsigned* __restrict__ ect,
                                                const int* __restrict__ rowptr,
                                                const unsigned short* __restrict__ xt,
                                                const float* __restrict__ bias,
                                                float* __restrict__ out, int n, int ldxt) {
  __shared__ float sm[4][256];
  const int lane = threadIdx.x & 63;
  const int wid = threadIdx.x >> 6;
  const int h = lane >> 5;
  const int sl = lane & 31;
  const int row = blockIdx.x * 4 + wid;
  if (row >= n) return;
  const int s = rowptr[row], e = rowptr[row + 1];
  const int cnt = e - s;
  float a[8] = {0.f, 0.f, 0.f, 0.f, 0.f, 0.f, 0.f, 0.f};
  unsigned myct = (s + lane < e) ? ect[s + lane] : 0u;
  int c1 = cnt > 64 ? 64 : cnt;
  for (int i = 0; i < c1; i += 2) {
    int j = i + h;
    unsigned ct = __shfl(myct, j);
    if (j < c1) {
      size_t base = (size_t)(ct & 0xFFFFFu) * ldxt + ((ct >> 20) << 8) + (sl << 3);
      short8 v = *(const short8*)(xt + base);
#pragma unroll
      for (int k = 0; k < 8; ++k) a[k] += b2f((unsigned short)v[k]);
    }
  }
  for (int i = s + 64; i < e; i += 2) {
    int j = i + h;
    if (j < e) {
      unsigned ct = ect[j];
      size_t base = (size_t)(ct & 0xFFFFFu) * ldxt + ((ct >> 20) << 8) + (sl << 3);
      short8 v = *(const short8*)(xt + base);
#pragma unroll
      for (int k = 0; k < 8; ++k) a[k] += b2f((unsigned short)v[k]);
    }
  }
#pragma unroll
  for (int k = 0; k < 8; ++k) a[k] += __shfl_xor(a[k], 32);
  if (h == 0) {
#pragma unroll
    for (int k = 0; k < 8; ++k) {
      int p8 = sl * 8 + k;
      int o = (p8 & 224) | ((p8 & 1) << 4) | ((p8 & 31) >> 1);
      sm[wid][o] = a[k];
    }
  }
  float4 v = *(const float4*)&sm[wid][lane * 4];
  float4 bb = ((const float4*)bias)[lane];
  float4 o;
  o.x = fmaxf(v.x + bb.x, 0.f);
  o.y = fmaxf(v.y + bb.y, 0.f);
  o.z = fmaxf(v.z + bb.z, 0.f);
  o.w = fmaxf(v.w + bb.w, 0.f);
  ((float4*)out)[(size_t)row * 64 + lane] = o;
}

extern "C" void kernel_launch(void* const* d_in, const int* in_sizes, int n_in,
                              void* d_out, int out_size, void* d_ws, size_t ws_size,
                              hipStream_t stream) {
  const float* x = (const float*)d_in[0];
  const int* ei = (const int*)d_in[1];
  const int* et = (const int*)d_in[2];
  const float* w = (const float*)d_in[3];
  const float* bias = (const float*)d_in[4];
  float* out = (float*)d_out;

  const int Nn = in_sizes[0] / D;        // 50000
  const int E = in_sizes[2];             // 800000
  const int R = in_sizes[3] / (D * D);   // 8
  const int Mpad = ((Nn + 63) / 64) * 64;   // 50048
  const int NC = R * D;                  // 2048

  char* p = (char*)d_ws;
  auto alloc = [&](size_t bytes) -> char* {
    char* q = p;
    p += (bytes + 255) & ~(size_t)255;
    return q;
  };
  unsigned short* xt = (unsigned short*)alloc((size_t)Mpad * NC * 2);
  unsigned short* xb = (unsigned short*)alloc((size_t)Mpad * D * 2);
  unsigned short* wt = (unsigned short*)alloc((size_t)NC * D * 2);
  int* rowptr = (int*)alloc((size_t)(Nn + 1) * 4);
  int* cursor = (int*)alloc((size_t)Nn * 4);
  int* deg = (int*)alloc((size_t)Nn * 4);
  int* bsum = (int*)alloc(1024);
  int* boff = (int*)alloc(1024);
  unsigned* ect = (unsigned*)alloc((size_t)E * 4);

  const int nsc = (Nn + 255) / 256;      // 196 (must be <= 256)
  long n_elems = (long)Nn * D;
  long pad_elems = (long)Mpad * D;
  int wtot = NC * D;
  int E_ = E, Nn_ = Nn, nsc_ = nsc;

  // one cooperative dispatch: converts + CSR build
  void* args[] = {(void*)&x, (void*)&xb, (void*)&n_elems, (void*)&pad_elems,
                  (void*)&w, (void*)&wt, (void*)&wtot,
                  (void*)&ei, (void*)&et, (void*)&E_,
                  (void*)&deg, (void*)&bsum, (void*)&boff, (void*)&rowptr,
                  (void*)&cursor, (void*)&ect, (void*)&Nn_, (void*)&nsc_};
  hipLaunchCooperativeKernel((void*)k_prep, dim3(1024), dim3(256), args, 0, stream);

  // dense transform
  hipLaunchKernelGGL(k_gemm, dim3(Mpad / 64, NC / (128 * NTY)), dim3(256), 0, stream,
                     xb, wt, xt, NC);

  // gather + bias + relu
  hipLaunchKernelGGL(k_gather, dim3((Nn + 3) / 4), dim3(256), 0, stream, ect, rowptr,
                     xt, bias, out, Nn, NC);
}

// Round 9
// 347.644 us; speedup vs baseline: 2.6342x; 2.6342x over previous
//
#include <hip/hip_runtime.h>
#include <hip/hip_bf16.h>
#include <stdint.h>

typedef __attribute__((ext_vector_type(8))) short short8;
typedef __attribute__((ext_vector_type(4))) float f32x4;

#define D 256
#define NTY 4  // y-tiles (128 cols) per gemm block

static __device__ __forceinline__ float b2f(unsigned short u) {
  union { unsigned u; float f; } c; c.u = ((unsigned)u) << 16; return c.f;
}
static __device__ __forceinline__ unsigned f2b(float f) {
  union { float f; unsigned u; } c; c.f = f;
  return (c.u + 0x7FFFu + ((c.u >> 16) & 1u)) >> 16;
}

// async global->LDS, 16B per lane, wave-uniform LDS base + lane*16
static __device__ __forceinline__ void gload16(const void* g, void* l) {
  __builtin_amdgcn_global_load_lds(
      (const __attribute__((address_space(1))) unsigned int*)g,
      (__attribute__((address_space(3))) unsigned int*)l, 16, 0, 0);
}

// ---- d1: cvt x (fp32->bf16, pad) | cvt W -> Wt[(r*256+o)][i] | deg atomics
// Three independent jobs packed into one dispatch (no ordering needed).
__global__ void k_cvt_deg(const float* __restrict__ x, unsigned short* __restrict__ xb,
                          long n_elems, long pad_elems, int xblocks,
                          const float* __restrict__ w, unsigned short* __restrict__ wt,
                          int wblocks,
                          const int* __restrict__ ei, int* deg, int E) {
  int bx = blockIdx.x;
  if (bx < xblocks) {
    long i4 = (long)bx * 256 + threadIdx.x;
    if (i4 * 4 >= pad_elems) return;
    ushort4 o;
    if (i4 * 4 < n_elems) {
      float4 v = ((const float4*)x)[i4];
      o.x = f2b(v.x); o.y = f2b(v.y); o.z = f2b(v.z); o.w = f2b(v.w);
    } else {
      o.x = 0; o.y = 0; o.z = 0; o.w = 0;
    }
    ((ushort4*)xb)[i4] = o;
  } else if (bx < xblocks + wblocks) {
    int t = (bx - xblocks) * 256 + threadIdx.x;
    int i = t & 255;         // k index
    int orow = t >> 8;       // r*256 + o
    int r = orow >> 8, o = orow & 255;
    wt[t] = (unsigned short)f2b(w[((size_t)(r * 256 + i)) * 256 + o]);
  } else {
    int e = (bx - xblocks - wblocks) * 256 + threadIdx.x;
    if (e < E) atomicAdd(&deg[ei[e]], 1);
  }
}

// ---- d2/d3: scan chain (round-6 proven, unchanged) ------------------------
__global__ void k_scan1(const int* __restrict__ deg, int* bsum, int n) {
  __shared__ int sm[256];
  int t = threadIdx.x, idx = blockIdx.x * 256 + t;
  sm[t] = idx < n ? deg[idx] : 0;
  __syncthreads();
  for (int off = 128; off; off >>= 1) {
    if (t < off) sm[t] += sm[t + off];
    __syncthreads();
  }
  if (t == 0) bsum[blockIdx.x] = sm[0];
}
__global__ void k_scan23(const int* __restrict__ deg, const int* __restrict__ bsum,
                         int* rowptr, int* cursor, int nsc, int n) {
  __shared__ int sb[256];
  __shared__ int sm[256];
  int t = threadIdx.x, idx = blockIdx.x * 256 + t;
  int bv = t < nsc ? bsum[t] : 0;
  sb[t] = bv;
  __syncthreads();
  for (int off = 1; off < 256; off <<= 1) {
    int x = t >= off ? sb[t - off] : 0;
    __syncthreads();
    sb[t] += x;
    __syncthreads();
  }
  int v = idx < n ? deg[idx] : 0;
  sm[t] = v;
  __syncthreads();
  for (int off = 1; off < 256; off <<= 1) {
    int x = t >= off ? sm[t - off] : 0;
    __syncthreads();
    sm[t] += x;
    __syncthreads();
  }
  int boff = sb[blockIdx.x] - bsum[blockIdx.x];  // exclusive block offset
  if (idx < n) {
    int e = boff + sm[t] - v;
    rowptr[idx] = e;
    cursor[idx] = e;
  }
  if (blockIdx.x == 0 && t == 0) rowptr[n] = sb[nsc - 1];
}

// ---- d4: gemm (round-5/6 proven, 91 µs) + bin blocks appended -------------
// gemm blocks: bx < gemmBlocks, mb = bx>>2, yb = bx&3 (was 2D grid 782x4).
// bin blocks (bx >= gemmBlocks) scatter edges; ~10 µs of work that needs only
// cursor (d3) and hides inside the gemm's ~4-round schedule.
__global__ __launch_bounds__(256) void k_gemm_bin(
    const unsigned short* __restrict__ A, const unsigned short* __restrict__ B,
    unsigned short* __restrict__ C, int ldc, int gemmBlocks,
    const int* __restrict__ ei, const int* __restrict__ et,
    int* cursor, unsigned* ect, int E) {
  __shared__ __align__(16) char lA[64 * 512];    // [64 rows][32 chunks of 16B]
  __shared__ __align__(16) char lB[128 * 128];   // [128 rows][8 chunks of 16B]
  const int bx = blockIdx.x;
  if (bx >= gemmBlocks) {
    int e = (bx - gemmBlocks) * 256 + threadIdx.x;
    if (e < E) {
      int r = ei[e], c = ei[E + e], ty = et[e];
      int pos = atomicAdd(&cursor[r], 1);
      ect[pos] = (unsigned)c | ((unsigned)ty << 20);
    }
    return;
  }
  const int t = threadIdx.x;
  const int lane = t & 63;
  const int wave = t >> 6;
  const int l15 = lane & 15, lhi = lane >> 4;
  const size_t tm = (size_t)(bx >> 2) * 64;
  const int y0 = (bx & 3) * NTY;

#pragma unroll
  for (int it = 0; it < 8; ++it) {
    int s = it * 256 + t;
    int row = s >> 5, c = s & 31;
    gload16(A + (tm + row) * 256 + ((c ^ (row & 7)) * 8),
            lA + (it * 256 + wave * 64) * 16);
  }

  for (int y = y0; y < y0 + NTY; ++y) {
    const int tn = y * 128;
    f32x4 acc[4][2];
#pragma unroll
    for (int a = 0; a < 4; ++a)
#pragma unroll
      for (int b = 0; b < 2; ++b)
#pragma unroll
        for (int e = 0; e < 4; ++e) acc[a][b][e] = 0.f;

    for (int kt = 0; kt < 256; kt += 64) {
      __syncthreads();
#pragma unroll
      for (int it = 0; it < 4; ++it) {
        int s = it * 256 + t;
        int row = s >> 3, c = s & 7;
        gload16(B + (tn + row) * 256 + kt + ((c ^ (row & 7)) * 8),
                lB + (it * 256 + wave * 64) * 16);
      }
      __syncthreads();

      short8 af[4][2], bfv[2][2];
      const int ktc = kt >> 3;
#pragma unroll
      for (int mi = 0; mi < 4; ++mi) {
#pragma unroll
        for (int kk = 0; kk < 2; ++kk) {
          int R = mi * 16 + l15;
          int c = ktc + kk * 4 + lhi;
          af[mi][kk] = *(const short8*)(lA + R * 512 + ((c ^ (R & 7)) * 16));
        }
      }
#pragma unroll
      for (int ni = 0; ni < 2; ++ni) {
#pragma unroll
        for (int kk = 0; kk < 2; ++kk) {
          int R2 = wave * 32 + ni * 16 + l15;
          int c2 = kk * 4 + lhi;
          bfv[ni][kk] = *(const short8*)(lB + R2 * 128 + ((c2 ^ (R2 & 7)) * 16));
        }
      }
#pragma unroll
      for (int mi = 0; mi < 4; ++mi) {
#pragma unroll
        for (int ni = 0; ni < 2; ++ni) {
          acc[mi][ni] = __builtin_amdgcn_mfma_f32_16x16x32_bf16(af[mi][0], bfv[ni][0], acc[mi][ni], 0, 0, 0);
          acc[mi][ni] = __builtin_amdgcn_mfma_f32_16x16x32_bf16(af[mi][1], bfv[ni][1], acc[mi][ni], 0, 0, 0);
        }
      }
    }
#pragma unroll
    for (int mi = 0; mi < 4; ++mi) {
#pragma unroll
      for (int j = 0; j < 4; ++j) {
        size_t row = tm + mi * 16 + lhi * 4 + j;
        unsigned pk = f2b(acc[mi][0][j]) | (f2b(acc[mi][1][j]) << 16);
        *(unsigned*)(C + row * (size_t)ldc + tn + wave * 32 + l15 * 2) = pk;
      }
    }
  }
}

// ---- d5: gather v2 (round-6 proven, unchanged) ----------------------------
__global__ __launch_bounds__(256) void k_gather(const unsigned* __restrict__ ect,
                                                const int* __restrict__ rowptr,
                                                const unsigned short* __restrict__ xt,
                                                const float* __restrict__ bias,
                                                float* __restrict__ out, int n, int ldxt) {
  __shared__ float sm[4][256];
  const int lane = threadIdx.x & 63;
  const int wid = threadIdx.x >> 6;
  const int h = lane >> 5;
  const int sl = lane & 31;
  const int row = blockIdx.x * 4 + wid;
  if (row >= n) return;
  const int s = rowptr[row], e = rowptr[row + 1];
  const int cnt = e - s;
  float a[8] = {0.f, 0.f, 0.f, 0.f, 0.f, 0.f, 0.f, 0.f};
  unsigned myct = (s + lane < e) ? ect[s + lane] : 0u;
  int c1 = cnt > 64 ? 64 : cnt;
  for (int i = 0; i < c1; i += 2) {
    int j = i + h;
    unsigned ct = __shfl(myct, j);
    if (j < c1) {
      size_t base = (size_t)(ct & 0xFFFFFu) * ldxt + ((ct >> 20) << 8) + (sl << 3);
      short8 v = *(const short8*)(xt + base);
#pragma unroll
      for (int k = 0; k < 8; ++k) a[k] += b2f((unsigned short)v[k]);
    }
  }
  for (int i = s + 64; i < e; i += 2) {
    int j = i + h;
    if (j < e) {
      unsigned ct = ect[j];
      size_t base = (size_t)(ct & 0xFFFFFu) * ldxt + ((ct >> 20) << 8) + (sl << 3);
      short8 v = *(const short8*)(xt + base);
#pragma unroll
      for (int k = 0; k < 8; ++k) a[k] += b2f((unsigned short)v[k]);
    }
  }
#pragma unroll
  for (int k = 0; k < 8; ++k) a[k] += __shfl_xor(a[k], 32);
  if (h == 0) {
#pragma unroll
    for (int k = 0; k < 8; ++k) {
      int p8 = sl * 8 + k;
      int o = (p8 & 224) | ((p8 & 1) << 4) | ((p8 & 31) >> 1);
      sm[wid][o] = a[k];
    }
  }
  float4 v = *(const float4*)&sm[wid][lane * 4];
  float4 bb = ((const float4*)bias)[lane];
  float4 o;
  o.x = fmaxf(v.x + bb.x, 0.f);
  o.y = fmaxf(v.y + bb.y, 0.f);
  o.z = fmaxf(v.z + bb.z, 0.f);
  o.w = fmaxf(v.w + bb.w, 0.f);
  ((float4*)out)[(size_t)row * 64 + lane] = o;
}

extern "C" void kernel_launch(void* const* d_in, const int* in_sizes, int n_in,
                              void* d_out, int out_size, void* d_ws, size_t ws_size,
                              hipStream_t stream) {
  const float* x = (const float*)d_in[0];
  const int* ei = (const int*)d_in[1];
  const int* et = (const int*)d_in[2];
  const float* w = (const float*)d_in[3];
  const float* bias = (const float*)d_in[4];
  float* out = (float*)d_out;

  const int Nn = in_sizes[0] / D;        // 50000
  const int E = in_sizes[2];             // 800000
  const int R = in_sizes[3] / (D * D);   // 8
  const int Mpad = ((Nn + 63) / 64) * 64;   // 50048
  const int NC = R * D;                  // 2048

  char* p = (char*)d_ws;
  auto alloc = [&](size_t bytes) -> char* {
    char* q = p;
    p += (bytes + 255) & ~(size_t)255;
    return q;
  };
  unsigned short* xt = (unsigned short*)alloc((size_t)Mpad * NC * 2);
  unsigned short* xb = (unsigned short*)alloc((size_t)Mpad * D * 2);
  unsigned short* wt = (unsigned short*)alloc((size_t)NC * D * 2);
  int* rowptr = (int*)alloc((size_t)(Nn + 1) * 4);
  int* cursor = (int*)alloc((size_t)Nn * 4);
  int* deg = (int*)alloc((size_t)Nn * 4);
  int* bsum = (int*)alloc(1024);
  unsigned* ect = (unsigned*)alloc((size_t)E * 4);

  const int nsc = (Nn + 255) / 256;      // 196
  const int xblocks = Mpad / 4;          // 12512
  const int wblocks = (NC * D) / 256;    // 2048
  const int eblocks = (E + 255) / 256;   // 3125
  const int gemmBlocks = (Mpad / 64) * 4;  // 3128

  hipMemsetAsync(deg, 0, (size_t)Nn * 4, stream);

  // d1: cvt-x | cvt-W | degree atomics (independent, one dispatch)
  hipLaunchKernelGGL(k_cvt_deg, dim3(xblocks + wblocks + eblocks), dim3(256), 0, stream,
                     x, xb, (long)Nn * D, (long)Mpad * D, xblocks,
                     w, wt, wblocks, ei, deg, E);
  // d2/d3: scan chain
  hipLaunchKernelGGL(k_scan1, dim3(nsc), dim3(256), 0, stream, deg, bsum, Nn);
  hipLaunchKernelGGL(k_scan23, dim3(nsc), dim3(256), 0, stream, deg, bsum,
                     rowptr, cursor, nsc, Nn);
  // d4: gemm + edge binning packed in one dispatch
  hipLaunchKernelGGL(k_gemm_bin, dim3(gemmBlocks + eblocks), dim3(256), 0, stream,
                     xb, wt, xt, NC, gemmBlocks, ei, et, cursor, ect, E);
  // d5: gather + bias + relu
  hipLaunchKernelGGL(k_gather, dim3((Nn + 3) / 4), dim3(256), 0, stream, ect, rowptr,
                     xt, bias, out, Nn, NC);
}